// Round 1
// baseline (237.426 us; speedup 1.0000x reference)
//
#include <hip/hip_runtime.h>
#include <math.h>

#define SH_C0 0.28209479177387814f
#define SH_C1 0.4886025119029199f
#define NEARP 0.01f
#define FARP 1e10f
#define LOWPASS 0.3f
#define ALPHA_MIN (1.0f/255.0f)
#define ALPHA_MAX 0.999f

// ws layout (floats): 10 unsorted SoA fields of length N, then key[N], then
// sorted AoS at ws + 11*N, stride 12 floats per gaussian:
// [mx, my, conA, conB, conC, op, r, g, b, dep, pad, pad]

__global__ void gs_preprocess(const float* __restrict__ means3d,
                              const float* __restrict__ quats,
                              const float* __restrict__ scales,
                              const float* __restrict__ opacities,
                              const float* __restrict__ sh,
                              const float* __restrict__ c2w,
                              const float* __restrict__ K,
                              int N, float* __restrict__ ws)
{
    int i = blockIdx.x * blockDim.x + threadIdx.x;
    if (i >= N) return;

    // viewmat = rigid inverse of camtoworld (row-major 4x4)
    float t0 = c2w[3], t1 = c2w[7], t2 = c2w[11];
    float Rw[3][3];
    Rw[0][0] = c2w[0]; Rw[0][1] = c2w[4]; Rw[0][2] = c2w[8];
    Rw[1][0] = c2w[1]; Rw[1][1] = c2w[5]; Rw[1][2] = c2w[9];
    Rw[2][0] = c2w[2]; Rw[2][1] = c2w[6]; Rw[2][2] = c2w[10];
    float tw0 = -(Rw[0][0]*t0 + Rw[0][1]*t1 + Rw[0][2]*t2);
    float tw1 = -(Rw[1][0]*t0 + Rw[1][1]*t1 + Rw[1][2]*t2);
    float tw2 = -(Rw[2][0]*t0 + Rw[2][1]*t1 + Rw[2][2]*t2);

    float fx = K[0], fy = K[4], cx = K[2], cy = K[5];

    float m0 = means3d[3*i+0], m1 = means3d[3*i+1], m2 = means3d[3*i+2];
    float x = Rw[0][0]*m0 + Rw[0][1]*m1 + Rw[0][2]*m2 + tw0;
    float y = Rw[1][0]*m0 + Rw[1][1]*m1 + Rw[1][2]*m2 + tw1;
    float z = Rw[2][0]*m0 + Rw[2][1]*m1 + Rw[2][2]*m2 + tw2;

    bool valid = (z > NEARP) && (z < FARP);
    float zs = valid ? z : 1.0f;
    float mean2x = fx * x / zs + cx;
    float mean2y = fy * y / zs + cy;

    // quaternion -> rotation
    float qw = quats[4*i+0], qx = quats[4*i+1], qy = quats[4*i+2], qz = quats[4*i+3];
    float qn = rsqrtf(qw*qw + qx*qx + qy*qy + qz*qz);
    qw *= qn; qx *= qn; qy *= qn; qz *= qn;
    float Rg[3][3];
    Rg[0][0] = 1.f - 2.f*(qy*qy + qz*qz); Rg[0][1] = 2.f*(qx*qy - qw*qz); Rg[0][2] = 2.f*(qx*qz + qw*qy);
    Rg[1][0] = 2.f*(qx*qy + qw*qz); Rg[1][1] = 1.f - 2.f*(qx*qx + qz*qz); Rg[1][2] = 2.f*(qy*qz - qw*qx);
    Rg[2][0] = 2.f*(qx*qz - qw*qy); Rg[2][1] = 2.f*(qy*qz + qw*qx); Rg[2][2] = 1.f - 2.f*(qx*qx + qy*qy);

    float sx = scales[3*i+0], sy = scales[3*i+1], sz = scales[3*i+2];
    float M[3][3];
    #pragma unroll
    for (int r = 0; r < 3; ++r) { M[r][0] = Rg[r][0]*sx; M[r][1] = Rg[r][1]*sy; M[r][2] = Rg[r][2]*sz; }

    // cov3d = M M^T (symmetric)
    float c3[3][3];
    #pragma unroll
    for (int r = 0; r < 3; ++r)
        #pragma unroll
        for (int c = 0; c < 3; ++c)
            c3[r][c] = M[r][0]*M[c][0] + M[r][1]*M[c][1] + M[r][2]*M[c][2];

    // cov_cam = Rw c3 Rw^T
    float Tm[3][3];
    #pragma unroll
    for (int r = 0; r < 3; ++r)
        #pragma unroll
        for (int c = 0; c < 3; ++c)
            Tm[r][c] = Rw[r][0]*c3[0][c] + Rw[r][1]*c3[1][c] + Rw[r][2]*c3[2][c];
    float cc[3][3];
    #pragma unroll
    for (int r = 0; r < 3; ++r)
        #pragma unroll
        for (int c = 0; c < 3; ++c)
            cc[r][c] = Tm[r][0]*Rw[c][0] + Tm[r][1]*Rw[c][1] + Tm[r][2]*Rw[c][2];

    // J (2x3 projection jacobian), cov2d = J cov_cam J^T
    float j00 = fx / zs;
    float j02 = -fx * x / (zs * zs);
    float j11 = fy / zs;
    float j12 = -fy * y / (zs * zs);
    // C*J0, C*J1 (C symmetric)
    float v00 = cc[0][0]*j00 + cc[0][2]*j02;
    float v02 = cc[2][0]*j00 + cc[2][2]*j02;
    float v10 = cc[0][1]*j11 + cc[0][2]*j12;
    float v12 = cc[2][1]*j11 + cc[2][2]*j12;
    float c2d00 = j00*v00 + j02*v02;
    float c2d01 = j00*v10 + j02*v12;
    float c2d11 = j11*(cc[1][1]*j11 + cc[1][2]*j12) + j12*v12;

    float a = c2d00 + LOWPASS;
    float b = c2d01;
    float c = c2d11 + LOWPASS;
    float det = a*c - b*b;
    valid = valid && (det > 0.f);
    float dets = (det > 0.f) ? det : 1.0f;
    float inv_det = 1.0f / dets;
    float conA = c * inv_det;
    float conB = -b * inv_det;
    float conC = a * inv_det;

    // SH degree-1 color
    float d0 = m0 - t0, d1 = m1 - t1, d2 = m2 - t2;
    float nrm = sqrtf(d0*d0 + d1*d1 + d2*d2);
    float inv_n = 1.0f / fmaxf(nrm, 1e-8f);
    float dxn = d0 * inv_n, dyn = d1 * inv_n, dzn = d2 * inv_n;
    const float* shi = sh + 12*i;
    float col[3];
    #pragma unroll
    for (int ch = 0; ch < 3; ++ch) {
        float v = SH_C0*shi[0*3+ch] - SH_C1*dyn*shi[1*3+ch]
                + SH_C1*dzn*shi[2*3+ch] - SH_C1*dxn*shi[3*3+ch];
        col[ch] = fmaxf(v + 0.5f, 0.0f);
    }

    float opa = 1.0f / (1.0f + __expf(-opacities[i]));
    float opv = valid ? opa : 0.0f;

    ws[0*N + i] = mean2x;
    ws[1*N + i] = mean2y;
    ws[2*N + i] = conA;
    ws[3*N + i] = conB;
    ws[4*N + i] = conC;
    ws[5*N + i] = opv;
    ws[6*N + i] = col[0];
    ws[7*N + i] = col[1];
    ws[8*N + i] = col[2];
    ws[9*N + i] = z;
    ws[10*N + i] = valid ? z : INFINITY;  // sort key
}

// single-block bitonic argsort over depth key, then gather SoA -> sorted AoS
__global__ void __launch_bounds__(1024) gs_sort(const float* __restrict__ ws,
                                                float* __restrict__ sorted, int N)
{
    __shared__ float skey[1024];
    __shared__ int   sidx[1024];
    int t = threadIdx.x;
    skey[t] = (t < N) ? ws[10*N + t] : INFINITY;
    sidx[t] = t;
    __syncthreads();
    for (int k = 2; k <= 1024; k <<= 1) {
        for (int j = k >> 1; j > 0; j >>= 1) {
            int ixj = t ^ j;
            if (ixj > t) {
                bool asc = ((t & k) == 0);
                float ka = skey[t], kb = skey[ixj];
                if ((ka > kb) == asc) {
                    skey[t] = kb; skey[ixj] = ka;
                    int tmp = sidx[t]; sidx[t] = sidx[ixj]; sidx[ixj] = tmp;
                }
            }
            __syncthreads();
        }
    }
    if (t < N) {
        int s = sidx[t];
        float* o = sorted + 12*t;
        #pragma unroll
        for (int f = 0; f < 10; ++f) o[f] = ws[f*N + s];
        o[10] = 0.f; o[11] = 0.f;
    }
}

__global__ void __launch_bounds__(256) gs_render(const float* __restrict__ sorted,
                                                 const int* __restrict__ wp,
                                                 const int* __restrict__ hp,
                                                 int N, float* __restrict__ out)
{
    __shared__ float sg[1024 * 12];
    int t = threadIdx.x;
    int W = *wp, H = *hp;

    // stage all sorted gaussians into LDS (N*12 floats, float4 loads)
    {
        const float4* src = (const float4*)sorted;
        float4* dst = (float4*)sg;
        int n4 = (N * 12) >> 2;
        for (int i = t; i < n4; i += 256) dst[i] = src[i];
    }
    __syncthreads();

    int WH = W * H;
    int p = blockIdx.x * 256 + t;
    if (p >= WH) return;

    float px = (float)(p % W) + 0.5f;
    float py = (float)(p / W) + 0.5f;

    float T = 1.0f, cr = 0.f, cg = 0.f, cb = 0.f, acc = 0.f, ed = 0.f;
    for (int j = 0; j < N; ++j) {
        const float* g = sg + 12*j;
        float dx = px - g[0];
        float dy = py - g[1];
        float sigma = 0.5f*(g[2]*dx*dx + g[4]*dy*dy) + g[3]*dx*dy;
        float alpha = fminf(g[5] * __expf(-sigma), ALPHA_MAX);
        if (sigma >= 0.f && alpha >= ALPHA_MIN) {
            float w = alpha * T;
            cr = fmaf(w, g[6], cr);
            cg = fmaf(w, g[7], cg);
            cb = fmaf(w, g[8], cb);
            acc += w;
            ed = fmaf(w, g[9], ed);
            T *= (1.0f - alpha);
        }
        if (((j & 63) == 63) && __all(T < 1e-6f)) break;
    }
    float edv = ed / fmaxf(acc, 1e-10f);
    out[p*4+0] = cr;
    out[p*4+1] = cg;
    out[p*4+2] = cb;
    out[p*4+3] = edv;
    out[WH*4 + p] = acc;
}

extern "C" void kernel_launch(void* const* d_in, const int* in_sizes, int n_in,
                              void* d_out, int out_size, void* d_ws, size_t ws_size,
                              hipStream_t stream) {
    const float* means3d   = (const float*)d_in[0];
    const float* quats     = (const float*)d_in[1];
    const float* scales    = (const float*)d_in[2];
    const float* opacities = (const float*)d_in[3];
    const float* sh        = (const float*)d_in[4];
    const float* c2w       = (const float*)d_in[5];
    const float* K         = (const float*)d_in[6];
    const int*   wp        = (const int*)d_in[7];
    const int*   hp        = (const int*)d_in[8];

    int N = in_sizes[0] / 3;
    float* ws = (float*)d_ws;
    float* sorted = ws + 11 * N;   // 12*N floats

    gs_preprocess<<<(N + 255) / 256, 256, 0, stream>>>(
        means3d, quats, scales, opacities, sh, c2w, K, N, ws);
    gs_sort<<<1, 1024, 0, stream>>>(ws, sorted, N);

    int WH = out_size / 5;  // 4 color channels + 1 alpha per pixel
    gs_render<<<(WH + 255) / 256, 256, 0, stream>>>(sorted, wp, hp, N, (float*)d_out);
}

// Round 2
// 110.501 us; speedup vs baseline: 2.1486x; 2.1486x over previous
//
#include <hip/hip_runtime.h>
#include <math.h>

#define SH_C0 0.28209479177387814f
#define SH_C1 0.4886025119029199f
#define NEARP 0.01f
#define FARP 1e10f
#define LOWPASS 0.3f
#define ALPHA_MIN (1.0f/255.0f)
#define ALPHA_MAX 0.999f

// ws layout (floats):
//   fields 0..10  : SoA arrays of length N: mx,my,conA,conB,conC,op,r,g,b,dep,radius
//   key           : @ 11N  (depth, INF when invalid)
//   sorted AoS    : @ 12N, stride 12: [mx,my,A,B,C,op,r,g,b,dep,0,0]
//   bbox float4   : @ 24N  (mx,my,radius,0) per sorted gaussian
// total 28N floats.

__global__ void gs_preprocess(const float* __restrict__ means3d,
                              const float* __restrict__ quats,
                              const float* __restrict__ scales,
                              const float* __restrict__ opacities,
                              const float* __restrict__ sh,
                              const float* __restrict__ c2w,
                              const float* __restrict__ K,
                              int N, float* __restrict__ ws)
{
    int i = blockIdx.x * blockDim.x + threadIdx.x;
    if (i >= N) return;

    // viewmat = rigid inverse of camtoworld (row-major 4x4)
    float t0 = c2w[3], t1 = c2w[7], t2 = c2w[11];
    float Rw[3][3];
    Rw[0][0] = c2w[0]; Rw[0][1] = c2w[4]; Rw[0][2] = c2w[8];
    Rw[1][0] = c2w[1]; Rw[1][1] = c2w[5]; Rw[1][2] = c2w[9];
    Rw[2][0] = c2w[2]; Rw[2][1] = c2w[6]; Rw[2][2] = c2w[10];
    float tw0 = -(Rw[0][0]*t0 + Rw[0][1]*t1 + Rw[0][2]*t2);
    float tw1 = -(Rw[1][0]*t0 + Rw[1][1]*t1 + Rw[1][2]*t2);
    float tw2 = -(Rw[2][0]*t0 + Rw[2][1]*t1 + Rw[2][2]*t2);

    float fx = K[0], fy = K[4], cx = K[2], cy = K[5];

    float m0 = means3d[3*i+0], m1 = means3d[3*i+1], m2 = means3d[3*i+2];
    float x = Rw[0][0]*m0 + Rw[0][1]*m1 + Rw[0][2]*m2 + tw0;
    float y = Rw[1][0]*m0 + Rw[1][1]*m1 + Rw[1][2]*m2 + tw1;
    float z = Rw[2][0]*m0 + Rw[2][1]*m1 + Rw[2][2]*m2 + tw2;

    bool valid = (z > NEARP) && (z < FARP);
    float zs = valid ? z : 1.0f;
    float mean2x = fx * x / zs + cx;
    float mean2y = fy * y / zs + cy;

    // quaternion -> rotation
    float qw = quats[4*i+0], qx = quats[4*i+1], qy = quats[4*i+2], qz = quats[4*i+3];
    float qn = rsqrtf(qw*qw + qx*qx + qy*qy + qz*qz);
    qw *= qn; qx *= qn; qy *= qn; qz *= qn;
    float Rg[3][3];
    Rg[0][0] = 1.f - 2.f*(qy*qy + qz*qz); Rg[0][1] = 2.f*(qx*qy - qw*qz); Rg[0][2] = 2.f*(qx*qz + qw*qy);
    Rg[1][0] = 2.f*(qx*qy + qw*qz); Rg[1][1] = 1.f - 2.f*(qx*qx + qz*qz); Rg[1][2] = 2.f*(qy*qz - qw*qx);
    Rg[2][0] = 2.f*(qx*qz - qw*qy); Rg[2][1] = 2.f*(qy*qz + qw*qx); Rg[2][2] = 1.f - 2.f*(qx*qx + qy*qy);

    float sx = scales[3*i+0], sy = scales[3*i+1], sz = scales[3*i+2];
    float M[3][3];
    #pragma unroll
    for (int r = 0; r < 3; ++r) { M[r][0] = Rg[r][0]*sx; M[r][1] = Rg[r][1]*sy; M[r][2] = Rg[r][2]*sz; }

    float c3[3][3];
    #pragma unroll
    for (int r = 0; r < 3; ++r)
        #pragma unroll
        for (int c = 0; c < 3; ++c)
            c3[r][c] = M[r][0]*M[c][0] + M[r][1]*M[c][1] + M[r][2]*M[c][2];

    float Tm[3][3];
    #pragma unroll
    for (int r = 0; r < 3; ++r)
        #pragma unroll
        for (int c = 0; c < 3; ++c)
            Tm[r][c] = Rw[r][0]*c3[0][c] + Rw[r][1]*c3[1][c] + Rw[r][2]*c3[2][c];
    float cc[3][3];
    #pragma unroll
    for (int r = 0; r < 3; ++r)
        #pragma unroll
        for (int c = 0; c < 3; ++c)
            cc[r][c] = Tm[r][0]*Rw[c][0] + Tm[r][1]*Rw[c][1] + Tm[r][2]*Rw[c][2];

    float j00 = fx / zs;
    float j02 = -fx * x / (zs * zs);
    float j11 = fy / zs;
    float j12 = -fy * y / (zs * zs);
    float v00 = cc[0][0]*j00 + cc[0][2]*j02;
    float v02 = cc[2][0]*j00 + cc[2][2]*j02;
    float v10 = cc[0][1]*j11 + cc[0][2]*j12;
    float v12 = cc[2][1]*j11 + cc[2][2]*j12;
    float c2d00 = j00*v00 + j02*v02;
    float c2d01 = j00*v10 + j02*v12;
    float c2d11 = j11*(cc[1][1]*j11 + cc[1][2]*j12) + j12*v12;

    float a = c2d00 + LOWPASS;
    float b = c2d01;
    float c = c2d11 + LOWPASS;
    float det = a*c - b*b;
    valid = valid && (det > 0.f);
    float dets = (det > 0.f) ? det : 1.0f;
    float inv_det = 1.0f / dets;
    float conA = c * inv_det;
    float conB = -b * inv_det;
    float conC = a * inv_det;

    // SH degree-1 color
    float d0 = m0 - t0, d1 = m1 - t1, d2 = m2 - t2;
    float nrm = sqrtf(d0*d0 + d1*d1 + d2*d2);
    float inv_n = 1.0f / fmaxf(nrm, 1e-8f);
    float dxn = d0 * inv_n, dyn = d1 * inv_n, dzn = d2 * inv_n;
    const float* shi = sh + 12*i;
    float col[3];
    #pragma unroll
    for (int ch = 0; ch < 3; ++ch) {
        float v = SH_C0*shi[0*3+ch] - SH_C1*dyn*shi[1*3+ch]
                + SH_C1*dzn*shi[2*3+ch] - SH_C1*dxn*shi[3*3+ch];
        col[ch] = fmaxf(v + 0.5f, 0.0f);
    }

    float opa = 1.0f / (1.0f + __expf(-opacities[i]));
    float opv = valid ? opa : 0.0f;

    // conservative cull radius: outside r, alpha < 1/255 provably
    // (sigma >= 0.5*|d|^2/lambda_max(cov2d))
    float lmax = 0.5f*(a + c) + sqrtf(0.25f*(a - c)*(a - c) + b*b);
    float rad = 0.f;
    if (valid && opv * 255.f > 1.0f) {
        float smax = logf(255.f * opv);
        rad = sqrtf(fmaxf(2.f * smax * lmax, 0.f)) * 1.02f + 0.1f; // small safety margin
    }

    ws[0*N + i] = mean2x;
    ws[1*N + i] = mean2y;
    ws[2*N + i] = conA;
    ws[3*N + i] = conB;
    ws[4*N + i] = conC;
    ws[5*N + i] = opv;
    ws[6*N + i] = col[0];
    ws[7*N + i] = col[1];
    ws[8*N + i] = col[2];
    ws[9*N + i] = z;
    ws[10*N + i] = rad;
    ws[11*N + i] = valid ? z : INFINITY;  // sort key
}

// rank sort: each thread counts keys ordered before its own (stable), then
// scatters its gaussian's record into sorted position directly.
__global__ void __launch_bounds__(256) gs_rank(const float* __restrict__ ws,
                                               float* __restrict__ sorted,
                                               float* __restrict__ bbox, int N)
{
    __shared__ float keys[2048];
    int t = threadIdx.x;
    int gid = blockIdx.x * 256 + t;
    for (int i = t; i < N; i += 256) keys[i] = ws[11*N + i];
    __syncthreads();
    if (gid >= N) return;
    float k = keys[gid];
    int rank = 0;
    for (int j = 0; j < N; ++j) {
        float kj = keys[j];
        rank += (int)((kj < k) || (kj == k && j < gid));
    }
    float mx  = ws[0*N+gid], my = ws[1*N+gid];
    float A   = ws[2*N+gid], B  = ws[3*N+gid], C = ws[4*N+gid];
    float op  = ws[5*N+gid];
    float r   = ws[6*N+gid], g  = ws[7*N+gid], b = ws[8*N+gid];
    float dep = ws[9*N+gid], rad = ws[10*N+gid];
    float* o = sorted + rank*12;
    o[0]=mx; o[1]=my; o[2]=A; o[3]=B; o[4]=C; o[5]=op;
    o[6]=r;  o[7]=g;  o[8]=b; o[9]=dep; o[10]=0.f; o[11]=0.f;
    ((float4*)bbox)[rank] = make_float4(mx, my, rad, 0.f);
}

// one 64-thread wave per 8x8 tile; ballot-compacted per-tile gaussian list.
__global__ void __launch_bounds__(64) gs_render(const float* __restrict__ sorted,
                                                const float* __restrict__ bbox,
                                                const int* __restrict__ wp,
                                                const int* __restrict__ hp,
                                                int N, float* __restrict__ out)
{
    __shared__ unsigned short list[2048];
    __shared__ float sg[128 * 12];
    int t = threadIdx.x;  // 0..63, one wave
    int W = *wp, H = *hp;
    int tiles_x = (W + 7) >> 3, tiles_y = (H + 7) >> 3;
    int total_tiles = tiles_x * tiles_y;
    int WH = W * H;
    const float4* bbox4   = (const float4*)bbox;
    const float4* sorted4 = (const float4*)sorted;

    for (int tile = blockIdx.x; tile < total_tiles; tile += gridDim.x) {
        int tx = tile % tiles_x, ty = tile / tiles_x;
        float tx0 = (float)(tx<<3) + 0.5f, tx1 = (float)(tx<<3) + 7.5f;
        float ty0 = (float)(ty<<3) + 0.5f, ty1 = (float)(ty<<3) + 7.5f;

        // --- binning: order-preserving wave compaction ---
        int count = 0;
        for (int b0 = 0; b0 < N; b0 += 64) {
            int g = b0 + t;
            bool hit = false;
            if (g < N) {
                float4 bb = bbox4[g];
                hit = (bb.z > 0.f)
                   && (bb.x - bb.z <= tx1) && (bb.x + bb.z >= tx0)
                   && (bb.y - bb.z <= ty1) && (bb.y + bb.z >= ty0);
            }
            unsigned long long mask = __ballot(hit);
            int pre = __popcll(mask & ((1ull << t) - 1ull));
            if (hit) list[count + pre] = (unsigned short)g;
            count += (int)__popcll(mask);
        }
        __syncthreads();

        int px_i = (tx<<3) + (t & 7);
        int py_i = (ty<<3) + (t >> 3);
        bool live = (px_i < W) && (py_i < H);
        float px = (float)px_i + 0.5f, py = (float)py_i + 0.5f;

        float T = live ? 1.0f : 0.0f;
        float cr=0.f, cg=0.f, cb=0.f, acc=0.f, ed=0.f;

        for (int c0 = 0; c0 < count; c0 += 128) {
            int cnt = min(128, count - c0);
            __syncthreads();
            // gather chunk records (3 float4 each) into LDS
            for (int i = t; i < cnt*3; i += 64) {
                int gi = list[c0 + i/3];
                ((float4*)sg)[i] = sorted4[gi*3 + (i - (i/3)*3)];
            }
            __syncthreads();
            for (int j = 0; j < cnt; ++j) {
                const float* g = sg + j*12;
                float dx = px - g[0], dy = py - g[1];
                float sigma = 0.5f*(g[2]*dx*dx + g[4]*dy*dy) + g[3]*dx*dy;
                float alpha = fminf(g[5]*__expf(-sigma), ALPHA_MAX);
                if (sigma >= 0.f && alpha >= ALPHA_MIN) {
                    float w = alpha * T;
                    cr = fmaf(w, g[6], cr);
                    cg = fmaf(w, g[7], cg);
                    cb = fmaf(w, g[8], cb);
                    acc += w;
                    ed = fmaf(w, g[9], ed);
                    T *= (1.0f - alpha);
                }
            }
            if (__all(T < 1e-6f)) break;
        }

        if (live) {
            int p = py_i * W + px_i;
            ((float4*)out)[p] = make_float4(cr, cg, cb, ed / fmaxf(acc, 1e-10f));
            out[WH*4 + p] = acc;
        }
        __syncthreads();
    }
}

extern "C" void kernel_launch(void* const* d_in, const int* in_sizes, int n_in,
                              void* d_out, int out_size, void* d_ws, size_t ws_size,
                              hipStream_t stream) {
    const float* means3d   = (const float*)d_in[0];
    const float* quats     = (const float*)d_in[1];
    const float* scales    = (const float*)d_in[2];
    const float* opacities = (const float*)d_in[3];
    const float* sh        = (const float*)d_in[4];
    const float* c2w       = (const float*)d_in[5];
    const float* K         = (const float*)d_in[6];
    const int*   wp        = (const int*)d_in[7];
    const int*   hp        = (const int*)d_in[8];

    int N = in_sizes[0] / 3;
    float* ws = (float*)d_ws;
    float* sorted = ws + 12 * N;   // 12N floats
    float* bbox   = ws + 24 * N;   // 4N floats

    gs_preprocess<<<(N + 255) / 256, 256, 0, stream>>>(
        means3d, quats, scales, opacities, sh, c2w, K, N, ws);
    gs_rank<<<(N + 255) / 256, 256, 0, stream>>>(ws, sorted, bbox, N);

    int WH = out_size / 5;  // 4 color channels + 1 alpha per pixel
    int nblocks = (WH + 63) / 64;  // == total tiles when W,H are multiples of 8
    gs_render<<<nblocks, 64, 0, stream>>>(sorted, bbox, wp, hp, N, (float*)d_out);
}